// Round 4
// baseline (167.322 us; speedup 1.0000x reference)
//
#include <hip/hip_runtime.h>

#ifndef __has_builtin
#define __has_builtin(x) 0
#endif

__device__ __forceinline__ float fexp2(float x) {
#if __has_builtin(__builtin_amdgcn_exp2f)
    return __builtin_amdgcn_exp2f(x);
#else
    return exp2f(x);
#endif
}
__device__ __forceinline__ float frcp(float x) {
#if __has_builtin(__builtin_amdgcn_rcpf)
    return __builtin_amdgcn_rcpf(x);
#else
    return 1.0f / x;
#endif
}

constexpr int TT = 32;    // directions T
constexpr int SS = 32;    // steps S
constexpr int BB = 64;    // graphs B
constexpr int NB = 64;    // partition blocks for edge sort
constexpr int CPB_N = 8;  // chunks per graph, node part
constexpr int CPB_E = 32; // chunks per graph, edge part
constexpr float FL = 50.0f * 1.44269504088896340736f;  // steepness * log2(e)

// ---- prep: graph bounds over sorted batch + per-block edge histogram + zero out ----
__global__ __launch_bounds__(256) void prep_k(
    const int* __restrict__ batch, const int* __restrict__ src,
    int N, int E, int nB,
    int* __restrict__ starts, int* __restrict__ hist, float* __restrict__ out)
{
    if ((int)blockIdx.x < nB) {
        const int n = blockIdx.x * 256 + threadIdx.x;
        if (n >= N) return;
        const int g = batch[n];
        const int gp = (n == 0) ? -1 : batch[n - 1];
        for (int g2 = gp + 1; g2 <= g; ++g2) starts[g2] = n;
        if (n == N - 1)
            for (int g2 = g + 1; g2 <= BB; ++g2) starts[g2] = N;
    } else {
        const int b = blockIdx.x - nB;      // 0..NB-1
        // zero the output slice for graph b (SS*TT = 1024 floats = 256 float4)
        float4* o4 = (float4*)(out + (size_t)b * SS * TT);
        o4[threadIdx.x] = float4{0.f, 0.f, 0.f, 0.f};
        __shared__ int h[BB];
        if (threadIdx.x < BB) h[threadIdx.x] = 0;
        __syncthreads();
        const int per = (E + NB - 1) / NB;
        const int lo = b * per, hi = min(E, lo + per);
        for (int e = lo + threadIdx.x; e < hi; e += 256)
            atomicAdd(&h[batch[src[e]]], 1);
        __syncthreads();
        if (threadIdx.x < BB) hist[b * BB + threadIdx.x] = h[threadIdx.x];
    }
}

// ---- scatter with per-block redundant scan (no separate scan kernel, no global atomics) ----
__global__ __launch_bounds__(256) void scatter_k(
    const int* __restrict__ src, const int* __restrict__ dst,
    const int* __restrict__ batch, int E,
    const int* __restrict__ hist,
    int* __restrict__ offs, int* __restrict__ ssrc, int* __restrict__ sdst)
{
    __shared__ int lcur[BB];
    __shared__ int stot[BB];
    const int tid = threadIdx.x;
    if (tid < BB) {
        int accb = 0, tot = 0;
        for (int b = 0; b < NB; ++b) {
            const int hv = hist[b * BB + tid];
            accb += (b < (int)blockIdx.x) ? hv : 0;
            tot += hv;
        }
        lcur[tid] = accb;
        stot[tid] = tot;
    }
    __syncthreads();
    if (tid == 0) {
        int run = 0;
        for (int i = 0; i < BB; ++i) { const int tv = stot[i]; stot[i] = run; run += tv; }
        if (blockIdx.x == 0) offs[BB] = run;
    }
    __syncthreads();
    if (tid < BB) {
        lcur[tid] += stot[tid];
        if (blockIdx.x == 0) offs[tid] = stot[tid];
    }
    __syncthreads();
    const int per = (E + NB - 1) / NB;
    const int lo = blockIdx.x * per, hi = min(E, lo + per);
    for (int e = lo + tid; e < hi; e += 256) {
        const int s = src[e], d = dst[e];
        const int pos = atomicAdd(&lcur[batch[s]], 1);
        ssrc[pos] = s;
        sdst[pos] = d;
    }
}

// ---- ECT pass: window-5 sigmoid + histogram suffix trick ----
// Thread owns (point-slot pr = tid>>5, t = tid&31). For each (point,t):
//   j = rint((h-l0)/dS); exact sigmoid for s in [j-2, j+2]; all s >= j+3 get +1
//   via cnt histogram, prefix-summed at block end. Tail error <= 1.4e-4/point.
__global__ __launch_bounds__(256) void ect_k(
    const float* __restrict__ x, const float* __restrict__ v,
    const float* __restrict__ lin,
    const int* __restrict__ ssrc, const int* __restrict__ sdst,
    const int* __restrict__ starts, const int* __restrict__ offs,
    float* __restrict__ out)
{
    __shared__ float accS[TT][SS + 1];   // transition corrections acc[t][s]
    __shared__ float cntS[TT][SS + 1];   // step counts cnt[t][b]
    for (int i = threadIdx.x; i < TT * (SS + 1); i += 256) {
        ((float*)accS)[i] = 0.f;
        ((float*)cntS)[i] = 0.f;
    }

    const bool edge = blockIdx.x >= BB * CPB_N;
    const int bid = edge ? blockIdx.x - BB * CPB_N : blockIdx.x;
    const int CPB = edge ? CPB_E : CPB_N;
    const int g = bid / CPB;
    const int c = bid % CPB;
    const int* bnds = edge ? offs : starts;
    const int s0 = bnds[g], s1 = bnds[g + 1];
    const int chunk = (s1 - s0 + CPB - 1) / CPB;
    const int lo = s0 + c * chunk;
    const int hi = min(s1, lo + chunk);

    const int t = threadIdx.x & 31;
    const int pr = threadIdx.x >> 5;
    const float v0 = v[t], v1 = v[TT + t], v2 = v[2 * TT + t];
    const float l0 = lin[0];
    const float dS = lin[1] - l0;
    const float invD = frcp(dS);
    const float fld = FL * dS;                    // ~5.12 exp2-units per bin
    const float pm2 = fexp2(2.f * fld), pm1 = fexp2(fld);
    const float pp1 = fexp2(-fld), pp2 = fexp2(-2.f * fld);
    __syncthreads();

    for (int base = lo; base < hi; base += 8) {
        const int p = base + pr;
        if (p < hi) {
            float h;
            if (edge) {
                const int sn = ssrc[p], dn = sdst[p];
                const float hs = fmaf(x[3 * sn], v0, fmaf(x[3 * sn + 1], v1, x[3 * sn + 2] * v2));
                const float hd = fmaf(x[3 * dn], v0, fmaf(x[3 * dn + 1], v1, x[3 * dn + 2] * v2));
                h = fmaxf(hs, hd);
            } else {
                h = fmaf(x[3 * p], v0, fmaf(x[3 * p + 1], v1, x[3 * p + 2] * v2));
            }
            const float hl0 = h - l0;
            float fj = rintf(hl0 * invD);
            fj = fminf(34.f, fmaxf(-3.f, fj));
            const int j = (int)fj;
            const float delta = fmaf(-fj, dS, hl0);      // h - l_j, |delta| <= dS/2 when unclamped
            const float ucen = fexp2(FL * delta);        // in [0.17, 5.9] when unclamped
            float sg[5];
            sg[0] = frcp(fmaf(ucen, pm2, 1.f));          // s = j-2
            sg[1] = frcp(fmaf(ucen, pm1, 1.f));          // s = j-1
            sg[2] = frcp(1.f + ucen);                    // s = j
            sg[3] = frcp(fmaf(ucen, pp1, 1.f));          // s = j+1
            sg[4] = frcp(fmaf(ucen, pp2, 1.f));          // s = j+2
            const int b = j + 3;                         // >= 0 (j clamped at -3)
            if (b < SS) atomicAdd(&cntS[t][b], 1.f);
#pragma unroll
            for (int m = 0; m < 5; ++m) {
                const int s = j - 2 + m;
                if (0 <= s && s < SS) atomicAdd(&accS[t][s], sg[m]);
            }
        }
    }
    __syncthreads();
    // per-t prefix over cnt bins -> full value per (t,s); reuse cntS as value buffer
    if (threadIdx.x < TT) {
        const int tt = threadIdx.x;
        float run = 0.f;
#pragma unroll
        for (int s = 0; s < SS; ++s) {
            run += cntS[tt][s];
            cntS[tt][s] = accS[tt][s] + run;
        }
    }
    __syncthreads();
    const float sign = edge ? -1.f : 1.f;
    float* o = out + (size_t)g * SS * TT;
#pragma unroll
    for (int k = 0; k < 4; ++k) {
        const int s = 4 * pr + k;
        atomicAdd(&o[s * TT + t], sign * cntS[t][s]);
    }
}

extern "C" void kernel_launch(void* const* d_in, const int* in_sizes, int n_in,
                              void* d_out, int out_size, void* d_ws, size_t ws_size,
                              hipStream_t stream) {
    const float* x   = (const float*)d_in[0];
    const float* v   = (const float*)d_in[1];
    const float* lin = (const float*)d_in[2];
    const int* edge_index = (const int*)d_in[3];
    const int* batch = (const int*)d_in[4];

    const int N = in_sizes[0] / 3;
    const int E = in_sizes[3] / 2;
    const int* src = edge_index;       // edge_index[0][:]
    const int* dst = edge_index + E;   // edge_index[1][:]
    float* out = (float*)d_out;

    char* ws = (char*)d_ws;
    int* starts = (int*)ws;                        // 65 ints
    int* offs   = (int*)(ws + 512);                // 65 ints
    int* hist   = (int*)(ws + 1024);               // NB*BB ints
    int* ssrc   = (int*)(ws + 65536);              // E ints
    int* sdst   = ssrc + E;                        // E ints

    const int nB = (N + 255) / 256;
    prep_k<<<nB + NB, 256, 0, stream>>>(batch, src, N, E, nB, starts, hist, out);
    scatter_k<<<NB, 256, 0, stream>>>(src, dst, batch, E, hist, offs, ssrc, sdst);
    ect_k<<<BB * (CPB_N + CPB_E), 256, 0, stream>>>(x, v, lin, ssrc, sdst, starts, offs, out);
}

// Round 5
// 37.632 us; speedup vs baseline: 4.4463x; 4.4463x over previous
//
#include <hip/hip_runtime.h>

#ifndef __has_builtin
#define __has_builtin(x) 0
#endif

__device__ __forceinline__ float fexp2(float x) {
#if __has_builtin(__builtin_amdgcn_exp2f)
    return __builtin_amdgcn_exp2f(x);
#else
    return exp2f(x);
#endif
}
__device__ __forceinline__ float frcp(float x) {
#if __has_builtin(__builtin_amdgcn_rcpf)
    return __builtin_amdgcn_rcpf(x);
#else
    return 1.0f / x;
#endif
}

constexpr int TT = 32;    // directions T
constexpr int SS = 32;    // steps S
constexpr int BB = 64;    // graphs B
constexpr int NB = 64;    // partition blocks for edge sort
constexpr int CPB_N = 8;  // chunks per graph, node part
constexpr int CPB_E = 32; // chunks per graph, edge part
constexpr float FL = 50.0f * 1.44269504088896340736f;  // steepness * log2(e)
constexpr float QS = 65536.0f;                          // fixed-point scale 2^16
constexpr float IQS = 1.0f / 65536.0f;

// ---- prep: graph bounds over sorted batch + per-block edge histogram + zero out ----
__global__ __launch_bounds__(256) void prep_k(
    const int* __restrict__ batch, const int* __restrict__ src,
    int N, int E, int nB,
    int* __restrict__ starts, int* __restrict__ hist, float* __restrict__ out)
{
    if ((int)blockIdx.x < nB) {
        const int n = blockIdx.x * 256 + threadIdx.x;
        if (n >= N) return;
        const int g = batch[n];
        const int gp = (n == 0) ? -1 : batch[n - 1];
        for (int g2 = gp + 1; g2 <= g; ++g2) starts[g2] = n;
        if (n == N - 1)
            for (int g2 = g + 1; g2 <= BB; ++g2) starts[g2] = N;
    } else {
        const int b = blockIdx.x - nB;      // 0..NB-1
        // zero the output slice for graph b (SS*TT = 1024 floats = 256 float4)
        float4* o4 = (float4*)(out + (size_t)b * SS * TT);
        o4[threadIdx.x] = float4{0.f, 0.f, 0.f, 0.f};
        __shared__ int h[BB];
        if (threadIdx.x < BB) h[threadIdx.x] = 0;
        __syncthreads();
        const int per = (E + NB - 1) / NB;
        const int lo = b * per, hi = min(E, lo + per);
        for (int e = lo + threadIdx.x; e < hi; e += 256)
            atomicAdd(&h[batch[src[e]]], 1);
        __syncthreads();
        if (threadIdx.x < BB) hist[b * BB + threadIdx.x] = h[threadIdx.x];
    }
}

// ---- scatter with per-block redundant scan (no global atomics) ----
__global__ __launch_bounds__(256) void scatter_k(
    const int* __restrict__ src, const int* __restrict__ dst,
    const int* __restrict__ batch, int E,
    const int* __restrict__ hist,
    int* __restrict__ offs, int* __restrict__ ssrc, int* __restrict__ sdst)
{
    __shared__ int lcur[BB];
    __shared__ int stot[BB];
    const int tid = threadIdx.x;
    if (tid < BB) {
        int accb = 0, tot = 0;
        for (int b = 0; b < NB; ++b) {
            const int hv = hist[b * BB + tid];
            accb += (b < (int)blockIdx.x) ? hv : 0;
            tot += hv;
        }
        lcur[tid] = accb;
        stot[tid] = tot;
    }
    __syncthreads();
    if (tid == 0) {
        int run = 0;
        for (int i = 0; i < BB; ++i) { const int tv = stot[i]; stot[i] = run; run += tv; }
        if (blockIdx.x == 0) offs[BB] = run;
    }
    __syncthreads();
    if (tid < BB) {
        lcur[tid] += stot[tid];
        if (blockIdx.x == 0) offs[tid] = stot[tid];
    }
    __syncthreads();
    const int per = (E + NB - 1) / NB;
    const int lo = blockIdx.x * per, hi = min(E, lo + per);
    for (int e = lo + tid; e < hi; e += 256) {
        const int s = src[e], d = dst[e];
        const int pos = atomicAdd(&lcur[batch[s]], 1);
        ssrc[pos] = s;
        sdst[pos] = d;
    }
}

// ---- ECT pass: window-5 sigmoid + histogram suffix trick, u32 fixed-point LDS atomics ----
// Thread owns (point-slot pr = tid>>5, t = tid&31). For each (point,t):
//   j = rint((h-l0)/dS); exact sigmoid (quantized to 2^-16) for s in [j-2, j+2];
//   all s >= j+3 get +1 via u32 cnt histogram, prefix-summed at block end.
__global__ __launch_bounds__(256) void ect_k(
    const float* __restrict__ x, const float* __restrict__ v,
    const float* __restrict__ lin,
    const int* __restrict__ ssrc, const int* __restrict__ sdst,
    const int* __restrict__ starts, const int* __restrict__ offs,
    float* __restrict__ out)
{
    __shared__ unsigned accS[TT][SS + 1];   // transition corrections, 2^16 fixed point
    __shared__ unsigned cntS[TT][SS + 1];   // step counts
    for (int i = threadIdx.x; i < TT * (SS + 1); i += 256) {
        ((unsigned*)accS)[i] = 0u;
        ((unsigned*)cntS)[i] = 0u;
    }

    const bool edge = blockIdx.x >= BB * CPB_N;
    const int bid = edge ? blockIdx.x - BB * CPB_N : blockIdx.x;
    const int CPB = edge ? CPB_E : CPB_N;
    const int g = bid / CPB;
    const int c = bid % CPB;
    const int* bnds = edge ? offs : starts;
    const int s0 = bnds[g], s1 = bnds[g + 1];
    const int chunk = (s1 - s0 + CPB - 1) / CPB;
    const int lo = s0 + c * chunk;
    const int hi = min(s1, lo + chunk);

    const int t = threadIdx.x & 31;
    const int pr = threadIdx.x >> 5;
    const float v0 = v[t], v1 = v[TT + t], v2 = v[2 * TT + t];
    const float l0 = lin[0];
    const float dS = lin[1] - l0;
    const float invD = frcp(dS);
    const float fld = FL * dS;                    // ~5.12 exp2-units per bin
    const float pm2 = fexp2(2.f * fld), pm1 = fexp2(fld);
    const float pp1 = fexp2(-fld), pp2 = fexp2(-2.f * fld);
    __syncthreads();

#pragma unroll 2
    for (int base = lo; base < hi; base += 8) {
        const int p = base + pr;
        if (p < hi) {
            float h;
            if (edge) {
                const int sn = ssrc[p], dn = sdst[p];
                const float hs = fmaf(x[3 * sn], v0, fmaf(x[3 * sn + 1], v1, x[3 * sn + 2] * v2));
                const float hd = fmaf(x[3 * dn], v0, fmaf(x[3 * dn + 1], v1, x[3 * dn + 2] * v2));
                h = fmaxf(hs, hd);
            } else {
                h = fmaf(x[3 * p], v0, fmaf(x[3 * p + 1], v1, x[3 * p + 2] * v2));
            }
            const float hl0 = h - l0;
            float fj = rintf(hl0 * invD);
            fj = fminf(34.f, fmaxf(-3.f, fj));
            const int j = (int)fj;
            const float delta = fmaf(-fj, dS, hl0);      // h - l_j
            const float ucen = fexp2(FL * delta);        // in [0.17, 5.9] when unclamped
            unsigned q[5];
            q[0] = (unsigned)__float2uint_rn(QS * frcp(fmaf(ucen, pm2, 1.f))); // s = j-2
            q[1] = (unsigned)__float2uint_rn(QS * frcp(fmaf(ucen, pm1, 1.f))); // s = j-1
            q[2] = (unsigned)__float2uint_rn(QS * frcp(1.f + ucen));           // s = j
            q[3] = (unsigned)__float2uint_rn(QS * frcp(fmaf(ucen, pp1, 1.f))); // s = j+1
            q[4] = (unsigned)__float2uint_rn(QS * frcp(fmaf(ucen, pp2, 1.f))); // s = j+2
            const int b = j + 3;                         // >= 0 (j clamped at -3)
            if (b < SS) atomicAdd(&cntS[t][b], 1u);
#pragma unroll
            for (int m = 0; m < 5; ++m) {
                const int s = j - 2 + m;
                if (0 <= s && s < SS) atomicAdd(&accS[t][s], q[m]);
            }
        }
    }
    __syncthreads();
    // per-t prefix over cnt bins -> full value per (t,s); write floats into cntS storage
    float* cval = (float*)cntS;
    if (threadIdx.x < TT) {
        const int tt = threadIdx.x;
        unsigned run = 0u;
#pragma unroll
        for (int s = 0; s < SS; ++s) {
            run += cntS[tt][s];
            const float vfull = fmaf((float)accS[tt][s], IQS, (float)run);
            cval[tt * (SS + 1) + s] = vfull;
        }
    }
    __syncthreads();
    const float sign = edge ? -1.f : 1.f;
    float* o = out + (size_t)g * SS * TT;
#pragma unroll
    for (int k = 0; k < 4; ++k) {
        const int s = 4 * pr + k;
        atomicAdd(&o[s * TT + t], sign * cval[t * (SS + 1) + s]);
    }
}

extern "C" void kernel_launch(void* const* d_in, const int* in_sizes, int n_in,
                              void* d_out, int out_size, void* d_ws, size_t ws_size,
                              hipStream_t stream) {
    const float* x   = (const float*)d_in[0];
    const float* v   = (const float*)d_in[1];
    const float* lin = (const float*)d_in[2];
    const int* edge_index = (const int*)d_in[3];
    const int* batch = (const int*)d_in[4];

    const int N = in_sizes[0] / 3;
    const int E = in_sizes[3] / 2;
    const int* src = edge_index;       // edge_index[0][:]
    const int* dst = edge_index + E;   // edge_index[1][:]
    float* out = (float*)d_out;

    char* ws = (char*)d_ws;
    int* starts = (int*)ws;                        // 65 ints
    int* offs   = (int*)(ws + 512);                // 65 ints
    int* hist   = (int*)(ws + 1024);               // NB*BB ints
    int* ssrc   = (int*)(ws + 65536);              // E ints
    int* sdst   = ssrc + E;                        // E ints

    const int nB = (N + 255) / 256;
    prep_k<<<nB + NB, 256, 0, stream>>>(batch, src, N, E, nB, starts, hist, out);
    scatter_k<<<NB, 256, 0, stream>>>(src, dst, batch, E, hist, offs, ssrc, sdst);
    ect_k<<<BB * (CPB_N + CPB_E), 256, 0, stream>>>(x, v, lin, ssrc, sdst, starts, offs, out);
}

// Round 6
// 34.329 us; speedup vs baseline: 4.8741x; 1.0962x over previous
//
#include <hip/hip_runtime.h>

#ifndef __has_builtin
#define __has_builtin(x) 0
#endif

__device__ __forceinline__ float fexp2(float x) {
#if __has_builtin(__builtin_amdgcn_exp2f)
    return __builtin_amdgcn_exp2f(x);
#else
    return exp2f(x);
#endif
}
__device__ __forceinline__ float frcp(float x) {
#if __has_builtin(__builtin_amdgcn_rcpf)
    return __builtin_amdgcn_rcpf(x);
#else
    return 1.0f / x;
#endif
}

constexpr int TT = 32;    // directions T
constexpr int SS = 32;    // steps S
constexpr int BB = 64;    // graphs B
constexpr int NB = 64;    // partition blocks for edge sort
constexpr int CPB_N = 8;  // chunks per graph, node part
constexpr int CPB_E = 16; // chunks per graph, edge part
constexpr float FL = 50.0f * 1.44269504088896340736f;  // steepness * log2(e)
constexpr float QS = 65536.0f;                          // fixed-point scale 2^16
constexpr float IQS = 1.0f / 65536.0f;

// ---- prep: graph bounds over sorted batch + per-block edge histogram + zero out ----
__global__ __launch_bounds__(256) void prep_k(
    const int* __restrict__ batch, const int* __restrict__ src,
    int N, int E, int nB,
    int* __restrict__ starts, int* __restrict__ hist, float* __restrict__ out)
{
    if ((int)blockIdx.x < nB) {
        const int n = blockIdx.x * 256 + threadIdx.x;
        if (n >= N) return;
        const int g = batch[n];
        const int gp = (n == 0) ? -1 : batch[n - 1];
        for (int g2 = gp + 1; g2 <= g; ++g2) starts[g2] = n;
        if (n == N - 1)
            for (int g2 = g + 1; g2 <= BB; ++g2) starts[g2] = N;
    } else {
        const int b = blockIdx.x - nB;      // 0..NB-1
        float4* o4 = (float4*)(out + (size_t)b * SS * TT);
        o4[threadIdx.x] = float4{0.f, 0.f, 0.f, 0.f};
        __shared__ int h[BB];
        if (threadIdx.x < BB) h[threadIdx.x] = 0;
        __syncthreads();
        const int per = (E + NB - 1) / NB;
        const int lo = b * per, hi = min(E, lo + per);
        for (int e = lo + threadIdx.x; e < hi; e += 256)
            atomicAdd(&h[batch[src[e]]], 1);
        __syncthreads();
        if (threadIdx.x < BB) hist[b * BB + threadIdx.x] = h[threadIdx.x];
    }
}

// ---- ECT core: window-3 sigmoid + histogram suffix, u32 fixed-point LDS atomics ----
// Thread owns (point-slot pr = tid>>5, t = tid&31). j = rint((h-l0)/dS);
// exact sigmoid for s in {j-1, j, j+1}; all s >= j+2 get +1 via cnt histogram.
// Epilogue: two-level scan (8 groups of 4 per t), direct global atomics.
__device__ __forceinline__ void ect_core(
    const float* __restrict__ x, const float* __restrict__ v,
    const float* __restrict__ lin,
    const int* __restrict__ ssrc, const int* __restrict__ sdst,
    bool edge, int lo, int hi, int g, float sign, float* __restrict__ out)
{
    __shared__ unsigned accS[TT][SS + 1];
    __shared__ unsigned cntS[TT][SS + 1];
    __shared__ unsigned part[TT][9];
    for (int i = threadIdx.x; i < TT * (SS + 1); i += 256) {
        ((unsigned*)accS)[i] = 0u;
        ((unsigned*)cntS)[i] = 0u;
    }
    const int t = threadIdx.x & 31;
    const int pr = threadIdx.x >> 5;
    const float v0 = v[t], v1 = v[TT + t], v2 = v[2 * TT + t];
    const float l0 = lin[0];
    const float dS = lin[1] - l0;
    const float invD = frcp(dS);
    const float fld = FL * dS;                 // ~5.12 exp2-units per bin
    const float pm1 = fexp2(fld), pp1 = fexp2(-fld);
    __syncthreads();

#pragma unroll 4
    for (int base = lo; base < hi; base += 8) {
        const int p = base + pr;
        if (p < hi) {
            float h;
            if (edge) {
                const int sn = ssrc[p], dn = sdst[p];
                const float hs = fmaf(x[3 * sn], v0, fmaf(x[3 * sn + 1], v1, x[3 * sn + 2] * v2));
                const float hd = fmaf(x[3 * dn], v0, fmaf(x[3 * dn + 1], v1, x[3 * dn + 2] * v2));
                h = fmaxf(hs, hd);
            } else {
                h = fmaf(x[3 * p], v0, fmaf(x[3 * p + 1], v1, x[3 * p + 2] * v2));
            }
            const float hl0 = h - l0;
            float fj = rintf(hl0 * invD);
            fj = fminf(34.f, fmaxf(-2.f, fj));
            const int j = (int)fj;
            const float delta = fmaf(-fj, dS, hl0);   // h - l_j
            const float ucen = fexp2(FL * delta);     // in [0.17, 5.9] when unclamped
            const unsigned q0 = __float2uint_rn(QS * frcp(fmaf(ucen, pm1, 1.f))); // s=j-1
            const unsigned q1 = __float2uint_rn(QS * frcp(1.f + ucen));           // s=j
            const unsigned q2 = __float2uint_rn(QS * frcp(fmaf(ucen, pp1, 1.f))); // s=j+1
            const int b = j + 2;
            if (b < SS) atomicAdd(&cntS[t][b], 1u);
            if (1 <= j && j <= SS) atomicAdd(&accS[t][j - 1], q0);
            if (0 <= j && j < SS)  atomicAdd(&accS[t][j], q1);
            if (-1 <= j && j < SS - 1) atomicAdd(&accS[t][j + 1], q2);
        }
    }
    __syncthreads();
    // two-level scan: thread (t, q=pr) owns s in [4q, 4q+4)
    const unsigned c0 = cntS[t][4 * pr], c1 = cntS[t][4 * pr + 1];
    const unsigned c2 = cntS[t][4 * pr + 2], c3 = cntS[t][4 * pr + 3];
    part[t][pr + 1] = c0 + c1 + c2 + c3;
    if (pr == 0) part[t][0] = 0u;
    __syncthreads();
    if (pr == 0) {
        unsigned r = 0u;
#pragma unroll
        for (int q = 1; q <= 8; ++q) { r += part[t][q]; part[t][q] = r; }
    }
    __syncthreads();
    unsigned run = part[t][pr];
    float* o = out + (size_t)g * SS * TT;
    run += c0;
    atomicAdd(&o[(4 * pr + 0) * TT + t], sign * fmaf((float)accS[t][4 * pr + 0], IQS, (float)run));
    run += c1;
    atomicAdd(&o[(4 * pr + 1) * TT + t], sign * fmaf((float)accS[t][4 * pr + 1], IQS, (float)run));
    run += c2;
    atomicAdd(&o[(4 * pr + 2) * TT + t], sign * fmaf((float)accS[t][4 * pr + 2], IQS, (float)run));
    run += c3;
    atomicAdd(&o[(4 * pr + 3) * TT + t], sign * fmaf((float)accS[t][4 * pr + 3], IQS, (float)run));
}

// ---- k2: scatter blocks (0..NB-1) overlapped with node-ect blocks ----
__global__ __launch_bounds__(256) void mid_k(
    const float* __restrict__ x, const float* __restrict__ v,
    const float* __restrict__ lin,
    const int* __restrict__ src, const int* __restrict__ dst,
    const int* __restrict__ batch, int E,
    const int* __restrict__ hist, int* __restrict__ offs,
    int* __restrict__ ssrc, int* __restrict__ sdst,
    const int* __restrict__ starts, float* __restrict__ out)
{
    if ((int)blockIdx.x < NB) {
        __shared__ int lcur[BB];
        __shared__ int stot[BB];
        const int tid = threadIdx.x;
        if (tid < BB) {
            int accb = 0, tot = 0;
            for (int b = 0; b < NB; ++b) {
                const int hv = hist[b * BB + tid];
                accb += (b < (int)blockIdx.x) ? hv : 0;
                tot += hv;
            }
            lcur[tid] = accb;
            stot[tid] = tot;
        }
        __syncthreads();
        if (tid == 0) {
            int run = 0;
            for (int i = 0; i < BB; ++i) { const int tv = stot[i]; stot[i] = run; run += tv; }
            if (blockIdx.x == 0) offs[BB] = run;
        }
        __syncthreads();
        if (tid < BB) {
            lcur[tid] += stot[tid];
            if (blockIdx.x == 0) offs[tid] = stot[tid];
        }
        __syncthreads();
        const int per = (E + NB - 1) / NB;
        const int lo = blockIdx.x * per, hi = min(E, lo + per);
        for (int e = lo + tid; e < hi; e += 256) {
            const int s = src[e], d = dst[e];
            const int pos = atomicAdd(&lcur[batch[s]], 1);
            ssrc[pos] = s;
            sdst[pos] = d;
        }
    } else {
        const int bid = blockIdx.x - NB;
        const int g = bid / CPB_N, c = bid % CPB_N;
        const int s0 = starts[g], s1 = starts[g + 1];
        const int chunk = (s1 - s0 + CPB_N - 1) / CPB_N;
        const int lo = s0 + c * chunk;
        const int hi = min(s1, lo + chunk);
        ect_core(x, v, lin, nullptr, nullptr, false, lo, hi, g, 1.0f, out);
    }
}

// ---- k3: edge-ect only ----
__global__ __launch_bounds__(256) void edge_k(
    const float* __restrict__ x, const float* __restrict__ v,
    const float* __restrict__ lin,
    const int* __restrict__ ssrc, const int* __restrict__ sdst,
    const int* __restrict__ offs, float* __restrict__ out)
{
    const int g = blockIdx.x / CPB_E, c = blockIdx.x % CPB_E;
    const int s0 = offs[g], s1 = offs[g + 1];
    const int chunk = (s1 - s0 + CPB_E - 1) / CPB_E;
    const int lo = s0 + c * chunk;
    const int hi = min(s1, lo + chunk);
    ect_core(x, v, lin, ssrc, sdst, true, lo, hi, g, -1.0f, out);
}

extern "C" void kernel_launch(void* const* d_in, const int* in_sizes, int n_in,
                              void* d_out, int out_size, void* d_ws, size_t ws_size,
                              hipStream_t stream) {
    const float* x   = (const float*)d_in[0];
    const float* v   = (const float*)d_in[1];
    const float* lin = (const float*)d_in[2];
    const int* edge_index = (const int*)d_in[3];
    const int* batch = (const int*)d_in[4];

    const int N = in_sizes[0] / 3;
    const int E = in_sizes[3] / 2;
    const int* src = edge_index;       // edge_index[0][:]
    const int* dst = edge_index + E;   // edge_index[1][:]
    float* out = (float*)d_out;

    char* ws = (char*)d_ws;
    int* starts = (int*)ws;                        // 65 ints
    int* offs   = (int*)(ws + 512);                // 65 ints
    int* hist   = (int*)(ws + 1024);               // NB*BB ints
    int* ssrc   = (int*)(ws + 65536);              // E ints
    int* sdst   = ssrc + E;                        // E ints

    const int nB = (N + 255) / 256;
    prep_k<<<nB + NB, 256, 0, stream>>>(batch, src, N, E, nB, starts, hist, out);
    mid_k<<<NB + BB * CPB_N, 256, 0, stream>>>(x, v, lin, src, dst, batch, E,
                                               hist, offs, ssrc, sdst, starts, out);
    edge_k<<<BB * CPB_E, 256, 0, stream>>>(x, v, lin, ssrc, sdst, offs, out);
}